// Round 3
// baseline (1432.575 us; speedup 1.0000x reference)
//
#include <hip/hip_runtime.h>

#define QDIM 4096
#define NDIM 50000
#define KDIM 1024
#define DDIM 256
#define NBLK 782          // ceil(NDIM/64)
#define TAU  0.25f        // refine margin: ~1000x the f32 screen noise

// ---- emulate numpy pairwise sum of squares for n=256 (two 128-halves, 8 accumulators)
__device__ float np_pairwise_sq(const float* a) {
#pragma clang fp contract(off)
    float res[2];
    for (int h = 0; h < 2; ++h) {
        const float* p = a + h * 128;
        float r0 = p[0] * p[0], r1 = p[1] * p[1], r2 = p[2] * p[2], r3 = p[3] * p[3];
        float r4 = p[4] * p[4], r5 = p[5] * p[5], r6 = p[6] * p[6], r7 = p[7] * p[7];
        for (int i = 8; i < 128; i += 8) {
            r0 += p[i + 0] * p[i + 0];
            r1 += p[i + 1] * p[i + 1];
            r2 += p[i + 2] * p[i + 2];
            r3 += p[i + 3] * p[i + 3];
            r4 += p[i + 4] * p[i + 4];
            r5 += p[i + 5] * p[i + 5];
            r6 += p[i + 6] * p[i + 6];
            r7 += p[i + 7] * p[i + 7];
        }
        res[h] = ((r0 + r1) + (r2 + r3)) + ((r4 + r5) + (r6 + r7));
    }
    return res[0] + res[1];
}

// ---------------------------------------------------------------- prep: c2np[k] (np-emulated), zero refCtr
__global__ __launch_bounds__(256) void prep_kernel(const float* __restrict__ cb,
                                                   float* __restrict__ c2np,
                                                   int* __restrict__ refCtr) {
    int k = blockIdx.x * 256 + threadIdx.x;
    if (k < KDIM) c2np[k] = np_pairwise_sq(cb + (size_t)k * DDIM);
    if (k == 0) *refCtr = 0;
}

// ---------------------------------------------------------------- S = query @ codebook^T  [4096 x 1024] f32
__global__ __launch_bounds__(256) void sgemm_kernel(const float* __restrict__ A,
                                                    const float* __restrict__ B,
                                                    float* __restrict__ S) {
    __shared__ float Xs[32][68];
    __shared__ float Cs[32][68];
    int tid = threadIdx.x;
    int tx = tid & 15, ty = tid >> 4;
    int rowBase = blockIdx.x * 64;
    int colBase = blockIdx.y * 64;
    float acc[4][4] = {};
    for (int dc = 0; dc < DDIM; dc += 32) {
#pragma unroll
        for (int i = 0; i < 8; ++i) {
            int ii = tid + i * 256;
            int d = ii & 31, r = ii >> 5;
            Xs[d][r] = A[(size_t)(rowBase + r) * DDIM + dc + d];
            Cs[d][r] = B[(size_t)(colBase + r) * DDIM + dc + d];
        }
        __syncthreads();
#pragma unroll
        for (int d = 0; d < 32; ++d) {
            float4 a = *(const float4*)&Xs[d][ty * 4];
            float4 b = *(const float4*)&Cs[d][tx * 4];
            float av[4] = {a.x, a.y, a.z, a.w};
            float bv[4] = {b.x, b.y, b.z, b.w};
#pragma unroll
            for (int r = 0; r < 4; ++r)
#pragma unroll
                for (int c = 0; c < 4; ++c) acc[r][c] += av[r] * bv[c];
        }
        __syncthreads();
    }
#pragma unroll
    for (int r = 0; r < 4; ++r) {
        float4 v = make_float4(acc[r][0], acc[r][1], acc[r][2], acc[r][3]);
        *(float4*)&S[(size_t)(rowBase + ty * 4 + r) * KDIM + colBase + tx * 4] = v;
    }
}

// ---------------------------------------------------------------- screen: distance-GEMM + argmin(+2nd) + loss partial
__global__ __launch_bounds__(256) void argmin_kernel(const float* __restrict__ E,
                                                     const float* __restrict__ CB,
                                                     const float* __restrict__ c2,
                                                     int* __restrict__ idxOut,
                                                     float* __restrict__ idxF,
                                                     float* __restrict__ lossPart,
                                                     int* __restrict__ refCtr,
                                                     int* __restrict__ refList) {
    __shared__ float Xs[32][68];
    __shared__ float Cs[32][68];
    __shared__ float xsq[64];
    __shared__ float rowd2[64];
    int tid = threadIdx.x;
    int tx = tid & 15, ty = tid >> 4;
    int rowBase = blockIdx.x * 64;
    float minv[4] = {1e30f, 1e30f, 1e30f, 1e30f};
    float min2[4] = {1e30f, 1e30f, 1e30f, 1e30f};
    int mini[4] = {0, 0, 0, 0};
    float x2p = 0.f;

    for (int kc = 0; kc < KDIM; kc += 64) {
        float acc[4][4] = {};
        for (int dc = 0; dc < DDIM; dc += 32) {
#pragma unroll
            for (int i = 0; i < 8; ++i) {
                int ii = tid + i * 256;
                int d = ii & 31, r = ii >> 5;
                int rg = rowBase + r;
                if (rg >= NDIM) rg = NDIM - 1;
                Xs[d][r] = E[(size_t)rg * DDIM + dc + d];
                Cs[d][r] = CB[(size_t)(kc + r) * DDIM + dc + d];
            }
            __syncthreads();
            if (kc == 0) {  // ||x||^2 from the staged tile, one pass over D
                int rr = tid >> 2, seg = tid & 3;
#pragma unroll
                for (int j = 0; j < 8; ++j) { float v = Xs[seg * 8 + j][rr]; x2p += v * v; }
            }
            float part[4][4] = {};
#pragma unroll
            for (int d = 0; d < 32; ++d) {
                float4 a = *(const float4*)&Xs[d][ty * 4];
                float4 b = *(const float4*)&Cs[d][tx * 4];
                float av[4] = {a.x, a.y, a.z, a.w};
                float bv[4] = {b.x, b.y, b.z, b.w};
#pragma unroll
                for (int r = 0; r < 4; ++r)
#pragma unroll
                    for (int c = 0; c < 4; ++c) part[r][c] += av[r] * bv[c];
            }
#pragma unroll
            for (int r = 0; r < 4; ++r)
#pragma unroll
                for (int c = 0; c < 4; ++c) acc[r][c] += part[r][c];
            __syncthreads();
        }
        if (kc == 0) {
            float p = x2p;
            p += __shfl_down(p, 2, 4);
            p += __shfl_down(p, 1, 4);
            if ((tid & 3) == 0) xsq[tid >> 2] = p;
        }
#pragma unroll
        for (int c = 0; c < 4; ++c) {
            int ki = kc + tx * 4 + c;
            float cc = c2[ki];
#pragma unroll
            for (int r = 0; r < 4; ++r) {
                float v = cc - 2.0f * acc[r][c];
                if (v < minv[r]) { min2[r] = minv[r]; minv[r] = v; mini[r] = ki; }
                else if (v < min2[r]) { min2[r] = v; }
            }
        }
    }
#pragma unroll
    for (int r = 0; r < 4; ++r) {
        for (int m = 8; m >= 1; m >>= 1) {
            float ov  = __shfl_xor(minv[r], m, 16);
            int   oi  = __shfl_xor(mini[r], m, 16);
            float ov2 = __shfl_xor(min2[r], m, 16);
            if (ov < minv[r] || (ov == minv[r] && oi < mini[r])) {
                min2[r] = fminf(minv[r], ov2);
                minv[r] = ov; mini[r] = oi;
            } else {
                min2[r] = fminf(min2[r], ov);
            }
        }
    }
    __syncthreads();
    if (tx == 0) {
#pragma unroll
        for (int r = 0; r < 4; ++r) {
            int row = rowBase + ty * 4 + r;
            float d2 = xsq[ty * 4 + r] + minv[r];
            if (row < NDIM) {
                idxOut[row] = mini[r];
                idxF[row] = (float)mini[r];
                rowd2[ty * 4 + r] = d2;
                if (min2[r] - minv[r] < TAU) {   // ambiguous in f32 -> np-exact re-argmin
                    int p = atomicAdd(refCtr, 1);
                    refList[p] = row;
                }
            } else {
                rowd2[ty * 4 + r] = 0.f;
            }
        }
    }
    __syncthreads();
    if (tid == 0) {
        float s = 0.f;
        for (int i = 0; i < 64; ++i) s += rowd2[i];
        lossPart[blockIdx.x] = s;   // deterministic: no atomics
    }
}

// ---------------------------------------------------------------- np-f32-exact re-argmin for flagged rows
__global__ __launch_bounds__(256) void refine_kernel(const float* __restrict__ E,
                                                     const float* __restrict__ CB,
                                                     const float* __restrict__ c2np,
                                                     const int* __restrict__ refCtr,
                                                     const int* __restrict__ refList,
                                                     int* __restrict__ idxOut,
                                                     float* __restrict__ idxF) {
    __shared__ float xrow[DDIM];
    __shared__ float x2sh;
    __shared__ float wval[4];
    __shared__ int widx[4];
    int tid = threadIdx.x;
    int count = *refCtr;
    if (count > NDIM) count = NDIM;
    for (int b = blockIdx.x; b < count; b += gridDim.x) {
        int row = refList[b];
        xrow[tid] = E[(size_t)row * DDIM + tid];
        __syncthreads();
        if (tid == 0) x2sh = np_pairwise_sq(xrow);   // numpy pairwise ||x||^2
        __syncthreads();
        float best = 1e30f;
        int bidx = 0x7fffffff;
#pragma unroll
        for (int kk = 0; kk < 4; ++kk) {
            int k = tid + kk * 256;
            const float* cp = CB + (size_t)k * DDIM;
            float dot = 0.f;                         // BLAS-style sequential FMA in d-order
            for (int d = 0; d < DDIM; ++d) dot = __builtin_fmaf(cp[d], xrow[d], dot);
            float t1 = x2sh + c2np[k];               // (x2 + c2) rounded, then - 2*dot (exact *2)
            float v = t1 - 2.0f * dot;
            if (v < best || (v == best && k < bidx)) { best = v; bidx = k; }
        }
        for (int m = 32; m >= 1; m >>= 1) {
            float ov = __shfl_xor(best, m, 64);
            int   oi = __shfl_xor(bidx, m, 64);
            if (ov < best || (ov == best && oi < bidx)) { best = ov; bidx = oi; }
        }
        if ((tid & 63) == 0) { wval[tid >> 6] = best; widx[tid >> 6] = bidx; }
        __syncthreads();
        if (tid == 0) {
            float bv = wval[0]; int bi = widx[0];
#pragma unroll
            for (int w = 1; w < 4; ++w)
                if (wval[w] < bv || (wval[w] == bv && widx[w] < bi)) { bv = wval[w]; bi = widx[w]; }
            idxOut[row] = bi;
            idxF[row] = (float)bi;
        }
        __syncthreads();
    }
}

// ---------------------------------------------------------------- loss finalize (deterministic serial sum)
__global__ void loss_kernel(const float* __restrict__ lossPart, float* __restrict__ out) {
    float s = 0.f;
    for (int i = 0; i < NBLK; ++i) s += lossPart[i];
    out[0] = 1.25f * s / (float)(NDIM * DDIM);   // (1 + beta) * mean
}

// ---------------------------------------------------------------- score[q][n] = S[q][idx[n]]  (819 MB streaming write)
__global__ __launch_bounds__(256) void gather_kernel(const float* __restrict__ S,
                                                     const int* __restrict__ idx,
                                                     float* __restrict__ score) {
    __shared__ float Srow[4 * 1024];
    int tid = threadIdx.x;
    int qBase = blockIdx.y * 4;
    int nBase = blockIdx.x * 2048;
#pragma unroll
    for (int i = 0; i < 4; ++i) {
        int o = (tid + i * 256) * 4;
        *(float4*)&Srow[o] = *(const float4*)&S[(size_t)qBase * KDIM + o];
    }
    __syncthreads();
#pragma unroll
    for (int s = 0; s < 2; ++s) {
        int n = nBase + s * 1024 + tid * 4;
        if (n < NDIM) {
            int4 id = *(const int4*)&idx[n];
#pragma unroll
            for (int q = 0; q < 4; ++q) {
                const float* sp = &Srow[q * 1024];
                float4 v = make_float4(sp[id.x], sp[id.y], sp[id.z], sp[id.w]);
                *(float4*)&score[(size_t)(qBase + q) * NDIM + n] = v;
            }
        }
    }
}

extern "C" void kernel_launch(void* const* d_in, const int* in_sizes, int n_in,
                              void* d_out, int out_size, void* d_ws, size_t ws_size,
                              hipStream_t stream) {
    const float* query  = (const float*)d_in[0];
    const float* entity = (const float*)d_in[1];
    const float* cb     = (const float*)d_in[2];
    float* out = (float*)d_out;
    char* ws = (char*)d_ws;

    float* S        = (float*)ws;                   // 16,777,216 B
    float* c2np     = (float*)(ws + 16777216);      //      4,096 B
    int*   idxW     = (int*)  (ws + 16781312);      //    200,000 B
    int*   refCtr   = (int*)  (ws + 16981312);      //          4 B
    int*   refList  = (int*)  (ws + 16981316);      //    200,000 B
    float* lossPart = (float*)(ws + 17181316);      //      3,128 B

    size_t QN = (size_t)QDIM * NDIM;
    float* score   = out;
    float* lossOut = out + QN;
    float* idxF    = out + QN + 1;

    prep_kernel<<<dim3(4), dim3(256), 0, stream>>>(cb, c2np, refCtr);
    sgemm_kernel<<<dim3(QDIM / 64, KDIM / 64), dim3(256), 0, stream>>>(query, cb, S);
    argmin_kernel<<<dim3(NBLK), dim3(256), 0, stream>>>(entity, cb, c2np, idxW, idxF,
                                                        lossPart, refCtr, refList);
    refine_kernel<<<dim3(256), dim3(256), 0, stream>>>(entity, cb, c2np, refCtr, refList, idxW, idxF);
    loss_kernel<<<dim3(1), dim3(1), 0, stream>>>(lossPart, lossOut);
    gather_kernel<<<dim3((NDIM + 2047) / 2048, QDIM / 4), dim3(256), 0, stream>>>(S, idxW, score);
}

// Round 4
// 536.827 us; speedup vs baseline: 2.6686x; 2.6686x over previous
//
#include <hip/hip_runtime.h>

#define QDIM 4096
#define NDIM 50000
#define KDIM 1024
#define DDIM 256
#define NBLK 782          // ceil(NDIM/64)
#define TAU  0.3f         // refine margin: ~16 sigma of the fp16 screen noise

typedef _Float16 half8 __attribute__((ext_vector_type(8)));
typedef float    f32x4 __attribute__((ext_vector_type(4)));

// ---- emulate numpy pairwise sum of squares for n=256 (two 128-halves, 8 accumulators)
__device__ float np_pairwise_sq(const float* a) {
#pragma clang fp contract(off)
    float res[2];
    for (int h = 0; h < 2; ++h) {
        const float* p = a + h * 128;
        float r0 = p[0] * p[0], r1 = p[1] * p[1], r2 = p[2] * p[2], r3 = p[3] * p[3];
        float r4 = p[4] * p[4], r5 = p[5] * p[5], r6 = p[6] * p[6], r7 = p[7] * p[7];
        for (int i = 8; i < 128; i += 8) {
            r0 += p[i + 0] * p[i + 0];
            r1 += p[i + 1] * p[i + 1];
            r2 += p[i + 2] * p[i + 2];
            r3 += p[i + 3] * p[i + 3];
            r4 += p[i + 4] * p[i + 4];
            r5 += p[i + 5] * p[i + 5];
            r6 += p[i + 6] * p[i + 6];
            r7 += p[i + 7] * p[i + 7];
        }
        res[h] = ((r0 + r1) + (r2 + r3)) + ((r4 + r5) + (r6 + r7));
    }
    return res[0] + res[1];
}

// ---------------------------------------------------------------- prep: c2np[k] (np-emulated), zero refCtr
__global__ __launch_bounds__(256) void prep_kernel(const float* __restrict__ cb,
                                                   float* __restrict__ c2np,
                                                   int* __restrict__ refCtr) {
    int k = blockIdx.x * 256 + threadIdx.x;
    if (k < KDIM) c2np[k] = np_pairwise_sq(cb + (size_t)k * DDIM);
    if (k == 0) *refCtr = 0;
}

// ---------------------------------------------------------------- codebook f32 -> fp16
__global__ __launch_bounds__(64) void cvt_kernel(const float* __restrict__ cb,
                                                 _Float16* __restrict__ cbh) {
    int k = blockIdx.x;
    int t = threadIdx.x;
    const float* src = cb + (size_t)k * DDIM + t * 4;
    _Float16* dst = cbh + (size_t)k * DDIM + t * 4;
    float4 v = *(const float4*)src;
    dst[0] = (_Float16)v.x; dst[1] = (_Float16)v.y;
    dst[2] = (_Float16)v.z; dst[3] = (_Float16)v.w;
}

// ==================== shared staging helpers (swizzle: 16B slot ^= row&7) ====================
// LDS layout per row: 256 halves = 32 slots of 8 halves; element d lives at
// slot (d>>3)^(row&7), offset d&7.  Fragment reads: lane&15 = row/col,
// k = (lane>>4)*8 + j within each K=32 slice s8  ->  slot = s8*4 + (lane>>4).

// ---------------------------------------------------------------- screen: fp16-MFMA distance GEMM + argmin(+2nd) + loss
__global__ __launch_bounds__(256) void argmin16_kernel(const float* __restrict__ E,
                                                       const _Float16* __restrict__ CBH,
                                                       const float* __restrict__ c2,
                                                       int* __restrict__ idxOut,
                                                       float* __restrict__ idxF,
                                                       float* __restrict__ lossPart,
                                                       int* __restrict__ refCtr,
                                                       int* __restrict__ refList) {
    __shared__ _Float16 As[64 * 256];
    __shared__ _Float16 Bs[64 * 256];
    __shared__ float xsq[64];
    __shared__ float rowd2s[64];
    int tid = threadIdx.x;
    int lane = tid & 63;
    int w = tid >> 6;                 // wave -> rows w*16..w*16+15
    int rowBase = blockIdx.x * 64;

    // ---- stage A (entity rows) f32 -> fp16 swizzled, accumulate ||x||^2 in f32
    {
        int r = tid >> 2, seg = tid & 3;
        int rg = rowBase + r; if (rg >= NDIM) rg = NDIM - 1;
        const float* src = E + (size_t)rg * DDIM + seg * 64;
        float x2p = 0.f;
#pragma unroll
        for (int i = 0; i < 8; ++i) {
            float4 v0 = *(const float4*)&src[i * 8];
            float4 v1 = *(const float4*)&src[i * 8 + 4];
            x2p += v0.x * v0.x + v0.y * v0.y + v0.z * v0.z + v0.w * v0.w;
            x2p += v1.x * v1.x + v1.y * v1.y + v1.z * v1.z + v1.w * v1.w;
            half8 h;
            h[0] = (_Float16)v0.x; h[1] = (_Float16)v0.y; h[2] = (_Float16)v0.z; h[3] = (_Float16)v0.w;
            h[4] = (_Float16)v1.x; h[5] = (_Float16)v1.y; h[6] = (_Float16)v1.z; h[7] = (_Float16)v1.w;
            int slot = (seg * 8 + i) ^ (r & 7);
            *(half8*)&As[r * 256 + slot * 8] = h;
        }
        x2p += __shfl_down(x2p, 2, 4);
        x2p += __shfl_down(x2p, 1, 4);
        if (seg == 0) xsq[r] = x2p;
    }
    __syncthreads();

    // ---- A fragments live in registers for all 16 chunks
    half8 a[8];
    {
        int rA = w * 16 + (lane & 15);
        int g = lane >> 4;
#pragma unroll
        for (int s8 = 0; s8 < 8; ++s8) {
            int slot = (s8 * 4 + g) ^ (rA & 7);
            a[s8] = *(half8*)&As[rA * 256 + slot * 8];
        }
    }

    float m1[4] = {1e30f, 1e30f, 1e30f, 1e30f};
    float m2[4] = {1e30f, 1e30f, 1e30f, 1e30f};
    int   mi[4] = {0, 0, 0, 0};

    for (int kc = 0; kc < 16; ++kc) {
        __syncthreads();              // everyone done reading Bs from prev chunk
        {   // stage B chunk (64 codes) fp16 global -> LDS swizzled
            int c = tid >> 2, seg = tid & 3;
            const _Float16* src = CBH + (size_t)(kc * 64 + c) * DDIM + seg * 64;
#pragma unroll
            for (int i = 0; i < 8; ++i) {
                half8 v = *(const half8*)&src[i * 8];
                int slot = (seg * 8 + i) ^ (c & 7);
                *(half8*)&Bs[c * 256 + slot * 8] = v;
            }
        }
        float cc[4];
#pragma unroll
        for (int t = 0; t < 4; ++t) cc[t] = c2[kc * 64 + t * 16 + (lane & 15)];
        __syncthreads();

        int g = lane >> 4;
#pragma unroll
        for (int t = 0; t < 4; ++t) {
            f32x4 acc = {0.f, 0.f, 0.f, 0.f};
            int cB = t * 16 + (lane & 15);
#pragma unroll
            for (int s8 = 0; s8 < 8; ++s8) {
                int slot = (s8 * 4 + g) ^ (cB & 7);
                half8 b = *(half8*)&Bs[cB * 256 + slot * 8];
                acc = __builtin_amdgcn_mfma_f32_16x16x32_f16(a[s8], b, acc, 0, 0, 0);
            }
            int ki = kc * 64 + cB;
#pragma unroll
            for (int j = 0; j < 4; ++j) {
                float v = cc[t] - 2.0f * acc[j];
                if (v < m1[j]) { m2[j] = m1[j]; m1[j] = v; mi[j] = ki; }
                else if (v < m2[j]) { m2[j] = v; }
            }
        }
    }
    // reduce (min1, idx, min2) across the 16 lanes holding the same rows (cols lane&15)
#pragma unroll
    for (int j = 0; j < 4; ++j) {
        for (int m = 8; m >= 1; m >>= 1) {
            float ov  = __shfl_xor(m1[j], m, 16);
            int   oi  = __shfl_xor(mi[j], m, 16);
            float ov2 = __shfl_xor(m2[j], m, 16);
            if (ov < m1[j] || (ov == m1[j] && oi < mi[j])) {
                m2[j] = fminf(m1[j], ov2);
                m1[j] = ov; mi[j] = oi;
            } else {
                m2[j] = fminf(m2[j], ov);
            }
        }
    }
    if ((lane & 15) == 0) {
#pragma unroll
        for (int j = 0; j < 4; ++j) {
            int rloc = w * 16 + (lane >> 4) * 4 + j;
            int row = rowBase + rloc;
            if (row < NDIM) {
                idxOut[row] = mi[j];
                idxF[row] = (float)mi[j];
                rowd2s[rloc] = xsq[rloc] + m1[j];
                if (m2[j] - m1[j] < TAU) {     // ambiguous under fp16 noise -> np-exact re-argmin
                    int p = atomicAdd(refCtr, 1);
                    refList[p] = row;
                }
            } else {
                rowd2s[rloc] = 0.f;
            }
        }
    }
    __syncthreads();
    if (tid == 0) {
        float s = 0.f;
        for (int i = 0; i < 64; ++i) s += rowd2s[i];
        lossPart[blockIdx.x] = s;
    }
}

// ---------------------------------------------------------------- S = query @ codebook^T via fp16 MFMA (threshold 20.48)
__global__ __launch_bounds__(256) void sgemm16_kernel(const float* __restrict__ Q,
                                                      const _Float16* __restrict__ CBH,
                                                      float* __restrict__ S) {
    __shared__ _Float16 As[64 * 256];
    __shared__ _Float16 Bs[64 * 256];
    int tid = threadIdx.x;
    int lane = tid & 63;
    int w = tid >> 6;
    int rowBase = blockIdx.x * 64;

    {
        int r = tid >> 2, seg = tid & 3;
        const float* src = Q + (size_t)(rowBase + r) * DDIM + seg * 64;
#pragma unroll
        for (int i = 0; i < 8; ++i) {
            float4 v0 = *(const float4*)&src[i * 8];
            float4 v1 = *(const float4*)&src[i * 8 + 4];
            half8 h;
            h[0] = (_Float16)v0.x; h[1] = (_Float16)v0.y; h[2] = (_Float16)v0.z; h[3] = (_Float16)v0.w;
            h[4] = (_Float16)v1.x; h[5] = (_Float16)v1.y; h[6] = (_Float16)v1.z; h[7] = (_Float16)v1.w;
            int slot = (seg * 8 + i) ^ (r & 7);
            *(half8*)&As[r * 256 + slot * 8] = h;
        }
    }
    __syncthreads();
    half8 a[8];
    {
        int rA = w * 16 + (lane & 15);
        int g = lane >> 4;
#pragma unroll
        for (int s8 = 0; s8 < 8; ++s8) {
            int slot = (s8 * 4 + g) ^ (rA & 7);
            a[s8] = *(half8*)&As[rA * 256 + slot * 8];
        }
    }

    for (int kc = 0; kc < 16; ++kc) {
        __syncthreads();
        {
            int c = tid >> 2, seg = tid & 3;
            const _Float16* src = CBH + (size_t)(kc * 64 + c) * DDIM + seg * 64;
#pragma unroll
            for (int i = 0; i < 8; ++i) {
                half8 v = *(const half8*)&src[i * 8];
                int slot = (seg * 8 + i) ^ (c & 7);
                *(half8*)&Bs[c * 256 + slot * 8] = v;
            }
        }
        __syncthreads();

        int g = lane >> 4;
#pragma unroll
        for (int t = 0; t < 4; ++t) {
            f32x4 acc = {0.f, 0.f, 0.f, 0.f};
            int cB = t * 16 + (lane & 15);
#pragma unroll
            for (int s8 = 0; s8 < 8; ++s8) {
                int slot = (s8 * 4 + g) ^ (cB & 7);
                half8 b = *(half8*)&Bs[cB * 256 + slot * 8];
                acc = __builtin_amdgcn_mfma_f32_16x16x32_f16(a[s8], b, acc, 0, 0, 0);
            }
#pragma unroll
            for (int j = 0; j < 4; ++j) {
                int row = rowBase + w * 16 + g * 4 + j;
                S[(size_t)row * KDIM + kc * 64 + cB] = acc[j];
            }
        }
    }
}

// ---------------------------------------------------------------- np-f32-exact re-argmin for flagged rows
__global__ __launch_bounds__(256) void refine_kernel(const float* __restrict__ E,
                                                     const float* __restrict__ CB,
                                                     const float* __restrict__ c2np,
                                                     const int* __restrict__ refCtr,
                                                     const int* __restrict__ refList,
                                                     int* __restrict__ idxOut,
                                                     float* __restrict__ idxF) {
    __shared__ float xrow[DDIM];
    __shared__ float x2sh;
    __shared__ float wval[4];
    __shared__ int widx[4];
    int tid = threadIdx.x;
    int count = *refCtr;
    if (count > NDIM) count = NDIM;
    for (int b = blockIdx.x; b < count; b += gridDim.x) {
        int row = refList[b];
        xrow[tid] = E[(size_t)row * DDIM + tid];
        __syncthreads();
        if (tid == 0) x2sh = np_pairwise_sq(xrow);
        __syncthreads();
        float best = 1e30f;
        int bidx = 0x7fffffff;
#pragma unroll
        for (int kk = 0; kk < 4; ++kk) {
            int k = tid + kk * 256;
            const float* cp = CB + (size_t)k * DDIM;
            float dot = 0.f;                    // BLAS-style sequential FMA in d-order
            for (int d = 0; d < DDIM; ++d) dot = __builtin_fmaf(cp[d], xrow[d], dot);
            float t1 = x2sh + c2np[k];
            float v = t1 - 2.0f * dot;
            if (v < best || (v == best && k < bidx)) { best = v; bidx = k; }
        }
        for (int m = 32; m >= 1; m >>= 1) {
            float ov = __shfl_xor(best, m, 64);
            int   oi = __shfl_xor(bidx, m, 64);
            if (ov < best || (ov == best && oi < bidx)) { best = ov; bidx = oi; }
        }
        if ((tid & 63) == 0) { wval[tid >> 6] = best; widx[tid >> 6] = bidx; }
        __syncthreads();
        if (tid == 0) {
            float bv = wval[0]; int bi = widx[0];
#pragma unroll
            for (int w = 1; w < 4; ++w)
                if (wval[w] < bv || (wval[w] == bv && widx[w] < bi)) { bv = wval[w]; bi = widx[w]; }
            idxOut[row] = bi;
            idxF[row] = (float)bi;
        }
        __syncthreads();
    }
}

// ---------------------------------------------------------------- loss finalize (deterministic fixed-order reduce)
__global__ void loss_kernel(const float* __restrict__ lossPart, float* __restrict__ out) {
    int t = threadIdx.x;
    float s = 0.f;
    for (int i = t; i < NBLK; i += 64) s += lossPart[i];
    for (int m = 32; m >= 1; m >>= 1) s += __shfl_down(s, m, 64);
    if (t == 0) out[0] = 1.25f * s / (float)(NDIM * DDIM);
}

// ---------------------------------------------------------------- score[q][n] = S[q][idx[n]]  (819 MB streaming write)
__global__ __launch_bounds__(256) void gather_kernel(const float* __restrict__ S,
                                                     const int* __restrict__ idx,
                                                     float* __restrict__ score) {
    __shared__ float Srow[4 * 1024];
    int tid = threadIdx.x;
    int qBase = blockIdx.y * 4;
    int nBase = blockIdx.x * 2048;
#pragma unroll
    for (int i = 0; i < 4; ++i) {
        int o = (tid + i * 256) * 4;
        *(float4*)&Srow[o] = *(const float4*)&S[(size_t)qBase * KDIM + o];
    }
    __syncthreads();
#pragma unroll
    for (int s = 0; s < 2; ++s) {
        int n = nBase + s * 1024 + tid * 4;
        if (n < NDIM) {
            int4 id = *(const int4*)&idx[n];
#pragma unroll
            for (int q = 0; q < 4; ++q) {
                const float* sp = &Srow[q * 1024];
                float4 v = make_float4(sp[id.x], sp[id.y], sp[id.z], sp[id.w]);
                *(float4*)&score[(size_t)(qBase + q) * NDIM + n] = v;
            }
        }
    }
}

extern "C" void kernel_launch(void* const* d_in, const int* in_sizes, int n_in,
                              void* d_out, int out_size, void* d_ws, size_t ws_size,
                              hipStream_t stream) {
    const float* query  = (const float*)d_in[0];
    const float* entity = (const float*)d_in[1];
    const float* cb     = (const float*)d_in[2];
    float* out = (float*)d_out;
    char* ws = (char*)d_ws;

    float*     S        = (float*)ws;                   // 16,777,216 B
    float*     c2np     = (float*)(ws + 16777216);      //      4,096 B
    int*       idxW     = (int*)  (ws + 16781312);      //    200,000 B
    int*       refCtr   = (int*)  (ws + 16981312);      //          4 B
    int*       refList  = (int*)  (ws + 16981316);      //    200,000 B
    float*     lossPart = (float*)(ws + 17181316);      //      3,128 B
    _Float16*  cbh      = (_Float16*)(ws + 17184448);   //    524,288 B

    size_t QN = (size_t)QDIM * NDIM;
    float* score   = out;
    float* lossOut = out + QN;
    float* idxF    = out + QN + 1;

    prep_kernel<<<dim3(4), dim3(256), 0, stream>>>(cb, c2np, refCtr);
    cvt_kernel<<<dim3(KDIM), dim3(64), 0, stream>>>(cb, cbh);
    sgemm16_kernel<<<dim3(QDIM / 64), dim3(256), 0, stream>>>(query, cbh, S);
    argmin16_kernel<<<dim3(NBLK), dim3(256), 0, stream>>>(entity, cbh, c2np, idxW, idxF,
                                                          lossPart, refCtr, refList);
    refine_kernel<<<dim3(256), dim3(256), 0, stream>>>(entity, cb, c2np, refCtr, refList, idxW, idxF);
    loss_kernel<<<dim3(1), dim3(64), 0, stream>>>(lossPart, lossOut);
    gather_kernel<<<dim3((NDIM + 2047) / 2048, QDIM / 4), dim3(256), 0, stream>>>(S, idxW, score);
}